// Round 10
// baseline (181.450 us; speedup 1.0000x reference)
//
#include <hip/hip_runtime.h>

// LSTM (B=8192, T=168, F=64, H=50) + MLP head, fused, f16 MFMA + fp32 state.
// Round 10: LDS-traffic cut (theory: LDS pipe-bound at ~12cy/b128).
// (1) xb eliminated -- x loaded global->register directly in A-frag layout
//     (4x f32x4/lane/step; L2 absorbs the 4-wave redundancy).
// (2) axb packed f16: 2x b128 per side instead of 4x b128 f32.
// Otherwise r7 structure: producer/consumer waves, merged-rcp exp2 gates,
// 1 lgkm-barrier/step, setprio on h-waves.

#define B_N 8192
#define T_N 168
#define F_N 64
#define H_N 50
#define HEAD_N 100
#define ROWSTRIDE (T_N * F_N)  // 10752

typedef _Float16 f16x8 __attribute__((ext_vector_type(8)));
typedef _Float16 f16x4 __attribute__((ext_vector_type(4)));
typedef float    f32x4 __attribute__((ext_vector_type(4)));

#define LOG2E  1.4426950408889634f
#define LOG2E2 2.8853900817779268f

#define MFMA __builtin_amdgcn_mfma_f32_16x16x32_f16

// LDS-only barrier: drain own LDS ops, barrier, compiler fence both sides.
#define BAR()                                                        \
    do {                                                             \
        asm volatile("s_waitcnt lgkmcnt(0)" ::: "memory");           \
        __builtin_amdgcn_s_barrier();                                \
        asm volatile("" ::: "memory");                               \
    } while (0)

__device__ __forceinline__ float rcp_f(float v) { return __builtin_amdgcn_rcpf(v); }
#if __has_builtin(__builtin_amdgcn_exp2f)
__device__ __forceinline__ float exp2_f(float v) { return __builtin_amdgcn_exp2f(v); }
#else
__device__ __forceinline__ float exp2_f(float v) { return __expf(0.6931471805599453f * v); }
#endif

__device__ __forceinline__ f16x8 cvt8(f32x4 a, f32x4 b) {
    f16x8 r;
    #pragma unroll
    for (int j = 0; j < 4; ++j) { r[j] = (_Float16)a[j]; r[4 + j] = (_Float16)b[j]; }
    return r;
}

__launch_bounds__(512, 4)
__global__ void lstm_fused(const float* __restrict__ x,
                           const float* __restrict__ Wx,
                           const float* __restrict__ Wh,
                           const float* __restrict__ b,
                           const float* __restrict__ W1,
                           const float* __restrict__ b1,
                           const float* __restrict__ W2,
                           const float* __restrict__ b2,
                           float* __restrict__ out)
{
    __shared__ alignas(16) _Float16 hb[2][16][72];          // hb[t&1] = h(t)
    __shared__ alignas(16) _Float16 axbh[2][4][2][64][8];   // [P][ut][pair][lane][8] f16
    __shared__ float hrelu[16][HEAD_N];

    const int tid  = threadIdx.x;
    const int lane = tid & 63;
    const int w    = tid >> 6;         // 0..7; 0-3 x-waves, 4-7 h-waves
    const int ut   = w & 3;            // unit-tile (16 units each)
    const int rowA = lane & 15;        // A-frag row == C-frag col
    const int kg   = lane >> 4;        // k-group 0..3
    const int R0   = blockIdx.x * 16;  // batch rows of this block
    const int jl   = ut * 16 + rowA;   // unit index 0..63
    const bool jv  = (jl < H_N);

    // ---- role-specific weight fragments (VGPR-resident, exp2-prescaled) --
    f16x8 wxf[4][2], whf[4][2];
    float bg[4];
    if (w < 4) {
        #pragma unroll
        for (int g = 0; g < 4; ++g) {
            const float sc = (g == 2) ? LOG2E2 : LOG2E;
            bg[g] = jv ? b[g * H_N + jl] * sc : 0.0f;
            #pragma unroll
            for (int ks = 0; ks < 2; ++ks) {
                f16x8 v;
                #pragma unroll
                for (int i = 0; i < 8; ++i) {
                    int k = ks * 32 + kg * 8 + i;     // same k-map as A-frags
                    v[i] = (_Float16)(jv ? Wx[k * 200 + g * H_N + jl] * sc : 0.0f);
                }
                wxf[g][ks] = v;
            }
        }
    } else {
        #pragma unroll
        for (int g = 0; g < 4; ++g) {
            const float sc = (g == 2) ? LOG2E2 : LOG2E;
            #pragma unroll
            for (int ks = 0; ks < 2; ++ks) {
                f16x8 v;
                #pragma unroll
                for (int i = 0; i < 8; ++i) {
                    int k = ks * 32 + kg * 8 + i;
                    v[i] = (_Float16)((jv && k < H_N) ? Wh[k * 200 + g * H_N + jl] * sc : 0.0f);
                }
                whf[g][ks] = v;
            }
        }
    }

    float c0 = 0.f, c1 = 0.f, c2 = 0.f, c3 = 0.f;   // h-wave fp32 cell state

    // zero h(0)
    for (int idx = tid; idx < 16 * 72; idx += 512)
        ((_Float16*)hb[0])[idx] = (_Float16)0.0f;

    // x-wave global A-frag base: row R0+rowA, col base kg*8 (f32 units).
    // Per step 4x f32x4 at offsets {0,4,32,36}: k = ks*32 + kg*8 + i.
    const float* xbase = x + (size_t)(R0 + rowA) * ROWSTRIDE + kg * 8;
    f32x4 xp0_0, xp0_1, xp0_2, xp0_3;   // x(t+1) frags for even-phase steps
    f32x4 xp1_0, xp1_1, xp1_2, xp1_3;   // x(t+1) frags for odd-phase steps
    const float* xldf = xbase + 3 * F_N;

    if (w < 4) {
        // x(0) temps + x(1)/x(2) into phase regs
        f32x4 t0 = *reinterpret_cast<const f32x4*>(xbase + 0);
        f32x4 t1 = *reinterpret_cast<const f32x4*>(xbase + 4);
        f32x4 t2 = *reinterpret_cast<const f32x4*>(xbase + 32);
        f32x4 t3 = *reinterpret_cast<const f32x4*>(xbase + 36);
        xp0_0 = *reinterpret_cast<const f32x4*>(xbase + F_N + 0);
        xp0_1 = *reinterpret_cast<const f32x4*>(xbase + F_N + 4);
        xp0_2 = *reinterpret_cast<const f32x4*>(xbase + F_N + 32);
        xp0_3 = *reinterpret_cast<const f32x4*>(xbase + F_N + 36);
        xp1_0 = *reinterpret_cast<const f32x4*>(xbase + 2 * F_N + 0);
        xp1_1 = *reinterpret_cast<const f32x4*>(xbase + 2 * F_N + 4);
        xp1_2 = *reinterpret_cast<const f32x4*>(xbase + 2 * F_N + 32);
        xp1_3 = *reinterpret_cast<const f32x4*>(xbase + 2 * F_N + 36);

        // prologue: ax(0) = b + x(0)@Wx -> axbh[0] (f16-packed)
        f16x8 xa0 = cvt8(t0, t1);
        f16x8 xa1 = cvt8(t2, t3);
        f32x4 a0 = {bg[0], bg[0], bg[0], bg[0]};
        f32x4 a1 = {bg[1], bg[1], bg[1], bg[1]};
        f32x4 a2 = {bg[2], bg[2], bg[2], bg[2]};
        f32x4 a3 = {bg[3], bg[3], bg[3], bg[3]};
        a0 = MFMA(xa0, wxf[0][0], a0, 0, 0, 0);
        a1 = MFMA(xa0, wxf[1][0], a1, 0, 0, 0);
        a2 = MFMA(xa0, wxf[2][0], a2, 0, 0, 0);
        a3 = MFMA(xa0, wxf[3][0], a3, 0, 0, 0);
        a0 = MFMA(xa1, wxf[0][1], a0, 0, 0, 0);
        a1 = MFMA(xa1, wxf[1][1], a1, 0, 0, 0);
        a2 = MFMA(xa1, wxf[2][1], a2, 0, 0, 0);
        a3 = MFMA(xa1, wxf[3][1], a3, 0, 0, 0);
        *reinterpret_cast<f16x8*>(&axbh[0][ut][0][lane][0]) = cvt8(a0, a1);
        *reinterpret_cast<f16x8*>(&axbh[0][ut][1][lane][0]) = cvt8(a2, a3);
    }
    __syncthreads();   // axbh[0] + hb[0] visible to h-waves

    // gates v2: merged-rcp pairs, exp2 domain (weights prescaled; g by 2x).
#define GATE1(PW, ii, cvar)                                                    \
    {                                                                          \
        float A_ = exp2_f(-zi[ii]);                                            \
        float B_ = exp2_f(-zg[ii]);                                            \
        float F_ = exp2_f(-zf[ii]);                                            \
        float sf_ = rcp_f(1.0f + F_);                                          \
        float r1_ = rcp_f((1.0f + A_) * (1.0f + B_));                          \
        float cn_ = fmaf(sf_, cvar, (1.0f - B_) * r1_);                        \
        cvar = cn_;                                                            \
        float C_ = exp2_f(-zo[ii]);                                            \
        float eD_ = fminf(-LOG2E2 * cn_, 80.0f);                               \
        float D_ = exp2_f(eD_);                                                \
        float r2_ = rcp_f((1.0f + C_) * (1.0f + D_));                          \
        hb[PW][kg * 4 + ii][jl] = (_Float16)((1.0f - D_) * r2_);               \
    }

    // x-wave step t (P=t&1): ax(t+1) from reg frags xp##P (= x(t+1));
    // write f16-packed axbh[P^1]; issue frag loads for x(t+3); barrier.
#define XSTEP(P, DO_LOAD)                                                      \
    {                                                                          \
        f16x8 xa0 = cvt8(xp##P##_0, xp##P##_1);                                \
        f16x8 xa1 = cvt8(xp##P##_2, xp##P##_3);                                \
        f32x4 a0 = {bg[0], bg[0], bg[0], bg[0]};                               \
        f32x4 a1 = {bg[1], bg[1], bg[1], bg[1]};                               \
        f32x4 a2 = {bg[2], bg[2], bg[2], bg[2]};                               \
        f32x4 a3 = {bg[3], bg[3], bg[3], bg[3]};                               \
        a0 = MFMA(xa0, wxf[0][0], a0, 0, 0, 0);                                \
        a1 = MFMA(xa0, wxf[1][0], a1, 0, 0, 0);                                \
        a2 = MFMA(xa0, wxf[2][0], a2, 0, 0, 0);                                \
        a3 = MFMA(xa0, wxf[3][0], a3, 0, 0, 0);                                \
        a0 = MFMA(xa1, wxf[0][1], a0, 0, 0, 0);                                \
        a1 = MFMA(xa1, wxf[1][1], a1, 0, 0, 0);                                \
        a2 = MFMA(xa1, wxf[2][1], a2, 0, 0, 0);                                \
        a3 = MFMA(xa1, wxf[3][1], a3, 0, 0, 0);                                \
        *reinterpret_cast<f16x8*>(&axbh[P ^ 1][ut][0][lane][0]) = cvt8(a0, a1);\
        *reinterpret_cast<f16x8*>(&axbh[P ^ 1][ut][1][lane][0]) = cvt8(a2, a3);\
        if (DO_LOAD) {                                                         \
            xp##P##_0 = *reinterpret_cast<const f32x4*>(xldf + 0);             \
            xp##P##_1 = *reinterpret_cast<const f32x4*>(xldf + 4);             \
            xp##P##_2 = *reinterpret_cast<const f32x4*>(xldf + 32);            \
            xp##P##_3 = *reinterpret_cast<const f32x4*>(xldf + 36);            \
            xldf += F_N;                                                       \
        }                                                                      \
        BAR();                                                                 \
    }

    // h-wave step t (P=t&1): z = axbh[P] (f16->f32) + h(t)@Wh; gates;
    // h(t+1) -> hb[P^1]; barrier.
#define HSTEP(P)                                                               \
    {                                                                          \
        __builtin_amdgcn_s_setprio(1);                                         \
        f16x8 ha0 = *reinterpret_cast<const f16x8*>(&hb[P][rowA][kg * 8]);     \
        f16x8 ha1 = *reinterpret_cast<const f16x8*>(&hb[P][rowA][32 + kg * 8]);\
        f16x8 r0 = *reinterpret_cast<const f16x8*>(&axbh[P][ut][0][lane][0]);  \
        f16x8 r1 = *reinterpret_cast<const f16x8*>(&axbh[P][ut][1][lane][0]);  \
        f32x4 zi, zf, zg, zo;                                                  \
        _Pragma("unroll")                                                      \
        for (int j = 0; j < 4; ++j) {                                          \
            zi[j] = (float)r0[j];  zf[j] = (float)r0[4 + j];                   \
            zg[j] = (float)r1[j];  zo[j] = (float)r1[4 + j];                   \
        }                                                                      \
        zi = MFMA(ha0, whf[0][0], zi, 0, 0, 0);                                \
        zf = MFMA(ha0, whf[1][0], zf, 0, 0, 0);                                \
        zg = MFMA(ha0, whf[2][0], zg, 0, 0, 0);                                \
        zo = MFMA(ha0, whf[3][0], zo, 0, 0, 0);                                \
        zi = MFMA(ha1, whf[0][1], zi, 0, 0, 0);                                \
        zf = MFMA(ha1, whf[1][1], zf, 0, 0, 0);                                \
        zg = MFMA(ha1, whf[2][1], zg, 0, 0, 0);                                \
        zo = MFMA(ha1, whf[3][1], zo, 0, 0, 0);                                \
        GATE1(P ^ 1, 0, c0)                                                    \
        GATE1(P ^ 1, 1, c1)                                                    \
        GATE1(P ^ 1, 2, c2)                                                    \
        GATE1(P ^ 1, 3, c3)                                                    \
        __builtin_amdgcn_s_setprio(0);                                         \
        BAR();                                                                 \
    }

    // Both role-loops execute EXACTLY 168 barriers (mirror structure).
    if (w < 4) {
        for (int it = 0; it < 82; ++it) {   // t = 0..163
            XSTEP(0, 1)
            XSTEP(1, 1)
        }
        XSTEP(0, 1)   // t=164: ax(165); loads x(167)
        XSTEP(1, 0)   // t=165: ax(166)
        XSTEP(0, 0)   // t=166: ax(167)
        BAR();        // t=167: x-waves just sync
    } else {
        for (int it = 0; it < 82; ++it) {   // t = 0..163
            HSTEP(0)
            HSTEP(1)
        }
        HSTEP(0)   // t=164
        HSTEP(1)   // t=165
        HSTEP(0)   // t=166
        HSTEP(1)   // t=167: final h(168) -> hb[0]
    }
#undef XSTEP
#undef HSTEP
#undef GATE1

    // ---- MLP head: relu(h@W1 + b1)@W2 + b2 + x[:, -1, 0] ------------------
    if (tid < 256) {
        const int r1 = tid & 15;
        const int u1 = tid >> 4;
        float hrow[H_N];
        #pragma unroll
        for (int k = 0; k < H_N; ++k) hrow[k] = (float)hb[0][r1][k];
        for (int uu = u1; uu < HEAD_N; uu += 16) {
            float s = b1[uu];
            #pragma unroll
            for (int k = 0; k < H_N; ++k) s += hrow[k] * W1[k * HEAD_N + uu];
            hrelu[r1][uu] = fmaxf(s, 0.0f);
        }
    }
    __syncthreads();
    if (tid < 256) {
        const int r2 = tid >> 4;
        const int p  = tid & 15;
        float s = 0.0f;
        for (int uu = p; uu < HEAD_N; uu += 16) s += hrelu[r2][uu] * W2[uu];
        #pragma unroll
        for (int off = 8; off > 0; off >>= 1) s += __shfl_xor(s, off, 16);
        if (p == 0) {
            float res = x[(size_t)(R0 + r2) * ROWSTRIDE + (T_N - 1) * F_N + 0];
            out[R0 + r2] = s + b2[0] + res;
        }
    }
}

extern "C" void kernel_launch(void* const* d_in, const int* in_sizes, int n_in,
                              void* d_out, int out_size, void* d_ws, size_t ws_size,
                              hipStream_t stream) {
    const float* x  = (const float*)d_in[0];
    const float* Wx = (const float*)d_in[1];
    const float* Wh = (const float*)d_in[2];
    const float* b  = (const float*)d_in[3];
    const float* W1 = (const float*)d_in[4];
    const float* b1 = (const float*)d_in[5];
    const float* W2 = (const float*)d_in[6];
    const float* b2 = (const float*)d_in[7];
    float* out = (float*)d_out;

    lstm_fused<<<dim3(B_N / 16), dim3(512), 0, stream>>>(x, Wx, Wh, b, W1, b1, W2, b2, out);
}